// Round 11
// baseline (161.582 us; speedup 1.0000x reference)
//
#include <hip/hip_runtime.h>
#include <math.h>

#define BB 4
#define NN 65536
#define G 64
#define G3 (G*G*G)
#define CF 32
#define HF 128
#define WF 128
#define VSc 0.05f
#define R2c 1.5625f   // 1.25^2, exactly representable

// d_ws layout (bytes):
//  [0, 2*B*G3)          : occ2[b][g][2] bytes: byte0 = inb, byte1 = inb&nearby   2 MB (memset 0)
//  BANY_OFF             : blockAny[1024] bytes, 1 per points-block (memset 0)
//  PART_OFF             : partials  (nearby-gated) [4096] float4 (fully written)
//  PART2_OFF            : partials2 (inb-gated)    [4096] float4 (fully written)
//  FMT_OFF              : fmapT[B][H][W][C] bf16                                  4.2 MB
//  W1P_OFF              : W1 packed bf16 fragments [2][4][4][16][8]               8 KB
//  W2P_OFF              : W2 packed bf16 fragments (k-permuted) [2][4][16][8]     2 KB
#define BANY_OFF (2*BB*G3)
#define PART_OFF (BANY_OFF + 1024)
#define PART2_OFF (PART_OFF + 4096*16)
#define FMT_OFF  (PART2_OFF + 4096*16)
#define FMT_SZ   (BB*HF*WF*CF*2)
#define W1P_OFF  (FMT_OFF + FMT_SZ)
#define W2P_OFF  (W1P_OFF + 8192)

typedef __attribute__((ext_vector_type(8))) short short8;
typedef __attribute__((ext_vector_type(4))) float floatx4;

__device__ __forceinline__ ushort f2bf(float x) {
    union { float f; unsigned u; } v; v.f = x;
    unsigned r = v.u + 0x7FFF + ((v.u >> 16) & 1);   // RNE
    return (ushort)(r >> 16);
}

// packed f32x2 -> bf16x2 (lo = first operand), RNE. T12 recipe.
__device__ __forceinline__ unsigned cvt_pk_bf16(float lo, float hi) {
    unsigned r;
    asm("v_cvt_pk_bf16_f32 %0, %1, %2" : "=v"(r) : "v"(lo), "v"(hi));
    return r;
}

// A-tile: 64 rows x 64 ushorts (128 B/row), XOR-swizzled at 16B granularity.
// ushort offset of (row, 16B-unit): unit' = unit ^ (row & 7)
// Correctness-verified in R6 and R8 (both passed, absmax identical).
#define AIDX(row, unit) (((row) << 6) + ((((unit) ^ ((row) & 7))) << 3))

// ---------- fused prep: points scatter (ZERO atomics) + fmap transpose + weight pack ----------
// blocks 0..1023   : points (256 pts each) -> occ2 plain byte stores + blockAny
// blocks 1024..2047: [B,C,H,W] f32 -> [B,H,W,C] bf16 transpose
// block 2048       : W1/W2 bf16 fragment pre-pack
__global__ __launch_bounds__(256) void prep_kernel(const float* __restrict__ pts,
                                                   const float* __restrict__ pelvis,
                                                   const float* __restrict__ fmap,
                                                   unsigned char* __restrict__ occ2,
                                                   unsigned char* __restrict__ blockAny,
                                                   ushort* __restrict__ fmapT,
                                                   const float* __restrict__ W1,
                                                   const float* __restrict__ W2,
                                                   ushort* __restrict__ w1p,
                                                   ushort* __restrict__ w2p) {
    __shared__ float tile[CF][65];
    int bi = blockIdx.x;

    if (bi < (BB * NN) / 256) {
        // ---- points path: racy same-value byte stores, no atomics anywhere ----
        int idx = bi * 256 + threadIdx.x;
        int b = idx >> 16;                             // N = 65536
        const float* p = pts + (size_t)idx * 3;
        float px = p[0], py = p[1], pz = p[2];
        float ax = pelvis[b * 3 + 0], ay = pelvis[b * 3 + 1], az = pelvis[b * 3 + 2];

        float dx = px - ax, dy = py - ay, dz = pz - az;
        float rxy = dx * dx + dy * dy;
        float d0 = dz * dz;
        float dm = (dz + 0.5f) * (dz + 0.5f);
        float dp = (dz - 0.5f) * (dz - 0.5f);
        float mind2 = rxy + fminf(d0, fminf(dm, dp));
        bool nearby = mind2 <= R2c;

        int vx = (int)floorf(px / VSc);
        int vy = (int)floorf(py / VSc);
        int vz = (int)floorf(pz / VSc);
        int v0x = (int)floorf(ax / VSc) - 32;
        int v0y = (int)floorf(ay / VSc) - 32;
        int v0z = (int)floorf(az / VSc) - 32;
        int lx = vx - v0x, ly = vy - v0y, lz = vz - v0z;
        bool inb = ((unsigned)lx < 64u) && ((unsigned)ly < 64u) && ((unsigned)lz < 64u);
        if (inb) {
            int flat = b * G3 + (lx << 12) + (ly << 6) + lz;
            if (nearby) {
                *(ushort*)(occ2 + 2 * (size_t)flat) = 0x0101;   // inb + nearby, one aligned store
            } else {
                occ2[2 * (size_t)flat] = 1;                      // inb only
            }
        }
        unsigned long long bal = __ballot(nearby);
        if ((threadIdx.x & 63) == 0 && bal != 0ULL) blockAny[bi] = 1;  // same-value race OK
        return;
    }

    if (bi == 2 * (BB * NN) / 256) {
        // ---- weight pre-pack path ----
        int t = threadIdx.x;
        // W1p: 512 short8 ; s = ((kt*4+nt)*4+quad)*16 + n16
        for (int s = t; s < 512; s += 256) {
            int kt = s >> 8, nt = (s >> 6) & 3, quad = (s >> 4) & 3, n16 = s & 15;
            short8 w;
#pragma unroll
            for (int j = 0; j < 8; ++j) {
                int kk = kt * 32 + quad * 8 + j;
                // feat k 0..31 -> W1 row 3+k ; feat k 32..34 -> W1 row k-32 ; else 0
                int row = (kk < 32) ? (3 + kk) : (kk - 32);
                w[j] = (kk < 35) ? (short)f2bf(W1[row * 64 + nt * 16 + n16]) : (short)0;
            }
            *(short8*)(w1p + s * 8) = w;
        }
        // W2p: 128 short8 ; physical k = kt*32+quad*8+j maps to logical h-col
        // c = (phys&3)*16 + (phys>>2)  (matches relu-store permutation p = n16*4+nt)
        if (t < 128) {
            int kt = t >> 6, quad = (t >> 4) & 3, n16 = t & 15;
            short8 w;
#pragma unroll
            for (int j = 0; j < 8; ++j) {
                int phys = kt * 32 + quad * 8 + j;
                int c = (phys & 3) * 16 + (phys >> 2);
                w[j] = (n16 < 12) ? (short)f2bf(W2[c * 12 + n16]) : (short)0;
            }
            *(short8*)(w2p + t * 8) = w;
        }
        return;
    }

    // ---- transpose path ----
    int tb = bi - (BB * NN) / 256;
    int xc = (tb & 1) * 64;
    int y  = (tb >> 1) & (HF - 1);
    int b  = tb >> 8;
    int t = threadIdx.x;
#pragma unroll
    for (int i = 0; i < 8; ++i) {
        int e = i * 256 + t;
        int c = e >> 6, p = e & 63;
        tile[c][p] = fmap[(((size_t)b * CF + c) * HF + y) * WF + xc + p];
    }
    __syncthreads();
    // 64 pixels x 32 ch = 1024 uints (bf16 pairs)
    unsigned* dst32 = (unsigned*)fmapT;
#pragma unroll
    for (int i = 0; i < 4; ++i) {
        int e = i * 256 + t;
        int pix = e >> 4, cp = e & 15;
        unsigned val = cvt_pk_bf16(tile[cp * 2][pix], tile[cp * 2 + 1][pix]);
        dst32[((((size_t)b * HF + y) * WF + xc + pix) << 4) + cp] = val;
    }
}

// ---------- voxel: bilinear gather (bf16) + MFMA MLP ----------
// Per wave: 64 voxels. A-tile [64 x 64] bf16 in LDS, 128 B/row, XOR-swizzled (8 KB/wave).
// Layer1: C1[64x64] = A(feat) * W1p ; Layer2 (cols permuted p=n16*4+nt): C2 = A(h) * W2p.
// Output: PLAIN cached stores, wave-coalesced via LDS O re-read -- each store instr
// covers a contiguous 1 KB span (16 full 64B lines), so merging never depends on L2
// residency. This removes R8's poison mechanism (partial-line eviction + write-allocate
// re-fetch), which is what previously made 5 blk/CU explode HBM traffic.
// LDS = 4*8192 = 32768 B exactly -> 5 blocks/CU (20 waves/CU).
__global__ __launch_bounds__(256, 5) void voxel_kernel(
    const ushort* __restrict__ fmapT, const float* __restrict__ pelvis,
    const float* __restrict__ Kmat, const float* __restrict__ bbx,
    const ushort* __restrict__ w1p, const ushort* __restrict__ w2p,
    const float* __restrict__ b1, const float* __restrict__ b2,
    const ushort* __restrict__ occ2,
    float4* __restrict__ partials, float4* __restrict__ partials2,
    float* __restrict__ outBig) {
    __shared__ __align__(16) char ldsRaw[4][8192];

    int blk = blockIdx.x;
    int b = blk >> 10;
    int wv = threadIdx.x >> 6, lane = threadIdx.x & 63;
    int quad = lane >> 4, n16 = lane & 15;
    int g = ((blk & 1023) << 8) + (wv << 6) + lane;
    ushort* A = (ushort*)ldsRaw[wv];

    // early load used only in the tail
    ushort oc2 = occ2[(size_t)b * G3 + g];   // lo byte = inb, hi byte = inb&nearby

    float ax = pelvis[b * 3 + 0], ay = pelvis[b * 3 + 1], az = pelvis[b * 3 + 2];
    float fx = Kmat[b * 9 + 0], fy = Kmat[b * 9 + 4];
    float cxp = Kmat[b * 9 + 2], cyp = Kmat[b * 9 + 5];
    float l = bbx[b * 4 + 0], t = bbx[b * 4 + 1];
    float r = bbx[b * 4 + 2], btm = bbx[b * 4 + 3];
    float inv_w = 1.0f / (r - l), inv_h = 1.0f / (btm - t);

    int v0x = (int)floorf(ax / VSc) - 32;
    int v0y = (int)floorf(ay / VSc) - 32;
    int v0z = (int)floorf(az / VSc) - 32;

    int gx = g >> 12, gy = (g >> 6) & 63, gz = g & 63;
    float cxx = (float)(v0x + gx) * VSc + 0.025f;
    float cyy = (float)(v0y + gy) * VSc + 0.025f;
    float czz = (float)(v0z + gz) * VSc + 0.025f;

    float z = czz;
    float u = cxx / z * fx + cxp;
    float vp = cyy / z * fy + cyp;
    float uu = (u - l) * inv_w * (float)(WF - 1);
    float vv = (vp - t) * inv_h * (float)(HF - 1);
    float x0f = floorf(uu), y0f = floorf(vv);
    float wx = uu - x0f, wy = vv - y0f;
    int x0 = (int)x0f, y0 = (int)y0f;
    int x1 = x0 + 1, y1 = y0 + 1;
    bool mx0 = (unsigned)x0 < (unsigned)WF;
    bool mx1 = (unsigned)x1 < (unsigned)WF;
    bool my0 = (unsigned)y0 < (unsigned)HF;
    bool my1 = (unsigned)y1 < (unsigned)HF;
    int xc0 = min(max(x0, 0), WF - 1), xc1 = min(max(x1, 0), WF - 1);
    int yc0 = min(max(y0, 0), HF - 1), yc1 = min(max(y1, 0), HF - 1);

    // ---- stage all 4 corners (bf16, 64B each) into registers ----
    const ushort* fb = fmapT + (size_t)b * HF * WF * CF;
    const uint4* q00 = (const uint4*)(fb + (size_t)(yc0 * WF + xc0) * CF);
    const uint4* q10 = (const uint4*)(fb + (size_t)(yc0 * WF + xc1) * CF);
    const uint4* q01 = (const uint4*)(fb + (size_t)(yc1 * WF + xc0) * CF);
    const uint4* q11 = (const uint4*)(fb + (size_t)(yc1 * WF + xc1) * CF);
    unsigned r00[16], r10[16], r01[16], r11[16];
#pragma unroll
    for (int j = 0; j < 4; ++j) {
        *(uint4*)(r00 + 4 * j) = q00[j];
        *(uint4*)(r10 + 4 * j) = q10[j];
        *(uint4*)(r01 + 4 * j) = q01[j];
        *(uint4*)(r11 + 4 * j) = q11[j];
    }

    float w00 = (1.0f - wx) * (1.0f - wy) * ((mx0 && my0) ? 1.0f : 0.0f);
    float w10 = wx * (1.0f - wy) * ((mx1 && my0) ? 1.0f : 0.0f);
    float w01 = (1.0f - wx) * wy * ((mx0 && my1) ? 1.0f : 0.0f);
    float w11 = wx * wy * ((mx1 && my1) ? 1.0f : 0.0f);

    // ---- bilinear combine in f32 (bf16 unpack = 1 VALU op each) ----
    float feat[35];
    feat[32] = ax - cxx;
    feat[33] = ay - cyy;
    feat[34] = az - czz;
#pragma unroll
    for (int d = 0; d < 16; ++d) {
        float a00l = __uint_as_float(r00[d] << 16), a00h = __uint_as_float(r00[d] & 0xFFFF0000u);
        float a10l = __uint_as_float(r10[d] << 16), a10h = __uint_as_float(r10[d] & 0xFFFF0000u);
        float a01l = __uint_as_float(r01[d] << 16), a01h = __uint_as_float(r01[d] & 0xFFFF0000u);
        float a11l = __uint_as_float(r11[d] << 16), a11h = __uint_as_float(r11[d] & 0xFFFF0000u);
        feat[2 * d]     = fmaf(a11l, w11, fmaf(a01l, w01, fmaf(a10l, w10, a00l * w00)));
        feat[2 * d + 1] = fmaf(a11h, w11, fmaf(a01h, w01, fmaf(a10h, w10, a00h * w00)));
    }

    // ---- pack feat -> bf16 LDS A-tile (K padded to 64, swizzled 16B units) ----
#pragma unroll
    for (int i = 0; i < 4; ++i) {
        uint4 v;
        v.x = cvt_pk_bf16(feat[8 * i + 0], feat[8 * i + 1]);
        v.y = cvt_pk_bf16(feat[8 * i + 2], feat[8 * i + 3]);
        v.z = cvt_pk_bf16(feat[8 * i + 4], feat[8 * i + 5]);
        v.w = cvt_pk_bf16(feat[8 * i + 6], feat[8 * i + 7]);
        *(uint4*)(A + AIDX(lane, i)) = v;
    }
    {
        uint4 v;
        v.x = cvt_pk_bf16(feat[32], feat[33]);
        v.y = cvt_pk_bf16(feat[34], 0.0f);
        v.z = 0; v.w = 0;
        *(uint4*)(A + AIDX(lane, 4)) = v;
        uint4 z4 = {0, 0, 0, 0};
        *(uint4*)(A + AIDX(lane, 5)) = z4;
        *(uint4*)(A + AIDX(lane, 6)) = z4;
        *(uint4*)(A + AIDX(lane, 7)) = z4;
    }

    // ---- weight B-fragments: coalesced 16B loads of pre-packed bf16 ----
    const short8* W1v = (const short8*)w1p;
    const short8* W2v = (const short8*)w2p;
    short8 B1f[2][4];
#pragma unroll
    for (int kt = 0; kt < 2; ++kt)
#pragma unroll
        for (int nt = 0; nt < 4; ++nt)
            B1f[kt][nt] = W1v[((kt * 4 + nt) * 4 + quad) * 16 + n16];
    short8 B2f[2];
#pragma unroll
    for (int kt = 0; kt < 2; ++kt)
        B2f[kt] = W2v[(kt * 4 + quad) * 16 + n16];
    float b1v[4];
#pragma unroll
    for (int nt = 0; nt < 4; ++nt) b1v[nt] = b1[nt * 16 + n16];
    float b2v = (n16 < 12) ? b2[n16] : 0.0f;

    // ---- layer 1: 32 MFMA ----
    floatx4 c1[4][4];
#pragma unroll
    for (int mt = 0; mt < 4; ++mt)
#pragma unroll
        for (int nt = 0; nt < 4; ++nt) {
            floatx4 c = {b1v[nt], b1v[nt], b1v[nt], b1v[nt]};
            c1[mt][nt] = c;
        }
#pragma unroll
    for (int mt = 0; mt < 4; ++mt) {
        int row = mt * 16 + n16;
        short8 a0 = *(short8*)(A + AIDX(row, quad));
        short8 a1 = *(short8*)(A + AIDX(row, 4 + quad));
#pragma unroll
        for (int nt = 0; nt < 4; ++nt) {
            c1[mt][nt] = __builtin_amdgcn_mfma_f32_16x16x32_bf16(a0, B1f[0][nt], c1[mt][nt], 0, 0, 0);
            c1[mt][nt] = __builtin_amdgcn_mfma_f32_16x16x32_bf16(a1, B1f[1][nt], c1[mt][nt], 0, 0, 0);
        }
    }

    // ---- relu -> bf16 -> LDS, nt-packed b64 writes (physical col p = n16*4+nt, swizzled) ----
#pragma unroll
    for (int mt = 0; mt < 4; ++mt)
#pragma unroll
        for (int rr = 0; rr < 4; ++rr) {
            float h0 = fmaxf(c1[mt][0][rr], 0.0f);
            float h1 = fmaxf(c1[mt][1][rr], 0.0f);
            float h2 = fmaxf(c1[mt][2][rr], 0.0f);
            float h3 = fmaxf(c1[mt][3][rr], 0.0f);
            uint2 uv;
            uv.x = cvt_pk_bf16(h0, h1);
            uv.y = cvt_pk_bf16(h2, h3);
            int row = mt * 16 + quad * 4 + rr;
            int addr = (row << 6) + ((((n16 >> 1) ^ (row & 7))) << 3) + ((n16 & 1) << 2);
            *(uint2*)(A + addr) = uv;
        }

    // ---- layer 2: 8 MFMA (W2 rows pre-permuted to match) ----
    floatx4 c2[4];
#pragma unroll
    for (int mt = 0; mt < 4; ++mt) {
        floatx4 c = {b2v, b2v, b2v, b2v};
        c2[mt] = c;
    }
#pragma unroll
    for (int mt = 0; mt < 4; ++mt) {
        int row = mt * 16 + n16;
        short8 a0 = *(short8*)(A + AIDX(row, quad));
        short8 a1 = *(short8*)(A + AIDX(row, 4 + quad));
        c2[mt] = __builtin_amdgcn_mfma_f32_16x16x32_bf16(a0, B2f[0], c2[mt], 0, 0, 0);
        c2[mt] = __builtin_amdgcn_mfma_f32_16x16x32_bf16(a1, B2f[1], c2[mt], 0, 0, 0);
    }

    // ---- C2 -> LDS (stride 20 floats, occupies [0, 5120) B of wave's region) ----
    float* O = (float*)ldsRaw[wv];
#pragma unroll
    for (int mt = 0; mt < 4; ++mt)
#pragma unroll
        for (int rr = 0; rr < 4; ++rr)
            O[(mt * 16 + quad * 4 + rr) * 20 + n16] = c2[mt][rr];

    // ---- wave-coalesced PLAIN output: 768 floats contiguous; lane i -> float4s i, i+64, i+128 ----
    // Each store instruction writes a contiguous 1 KB span = 16 full 64B lines.
    size_t base = (size_t)(b * G3 + ((blk & 1023) << 8) + (wv << 6)) * 12;
#pragma unroll
    for (int j = 0; j < 3; ++j) {
        int k = 4 * lane + 256 * j;          // float index within wave's 768-float block
        int vx12 = k / 12;                    // voxel within wave
        int c12 = k - vx12 * 12;              // component (0,4,8 - never crosses voxel)
        floatx4 val = *(floatx4*)(O + vx12 * 20 + c12);
        *(floatx4*)(outBig + base + k) = val;
    }

    // own voxel's out[0..3] for the softmax tail
    floatx4 o0 = *(floatx4*)(O + lane * 20);

    // ---- dual softmax accumulation, fixed max M = 1 ----
    float sig = 1.0f / (1.0f + __expf(-o0.x));
    float e = __expf(sig - 1.0f);
    float wxx = cxx + o0.y, wyy = cyy + o0.z, wzz = czz + o0.w;
    float eN = ((oc2 >> 8) != 0) ? e : 0.0f;      // nearby-gated (any==1 case)
    float eI = ((oc2 & 0xFF) != 0) ? e : 0.0f;    // inb-gated   (any==0 case)
    float sN0 = eN, sN1 = eN * wxx, sN2 = eN * wyy, sN3 = eN * wzz;
    float sI0 = eI, sI1 = eI * wxx, sI2 = eI * wyy, sI3 = eI * wzz;
#pragma unroll
    for (int off = 32; off > 0; off >>= 1) {
        sN0 += __shfl_down(sN0, off, 64);
        sN1 += __shfl_down(sN1, off, 64);
        sN2 += __shfl_down(sN2, off, 64);
        sN3 += __shfl_down(sN3, off, 64);
        sI0 += __shfl_down(sI0, off, 64);
        sI1 += __shfl_down(sI1, off, 64);
        sI2 += __shfl_down(sI2, off, 64);
        sI3 += __shfl_down(sI3, off, 64);
    }
    // red overlays the dead region of each wave's LDS (past O's 5120 B)
    float* redw = (float*)(ldsRaw[wv] + 5632);
    if ((threadIdx.x & 63) == 0) {
        redw[0] = sN0; redw[1] = sN1; redw[2] = sN2; redw[3] = sN3;
        redw[4] = sI0; redw[5] = sI1; redw[6] = sI2; redw[7] = sI3;
    }
    __syncthreads();
    if (threadIdx.x == 0) {
        float t0 = 0, t1 = 0, t2 = 0, t3 = 0, u0 = 0, u1 = 0, u2 = 0, u3 = 0;
#pragma unroll
        for (int w = 0; w < 4; ++w) {
            float* rw = (float*)(ldsRaw[w] + 5632);
            t0 += rw[0]; t1 += rw[1]; t2 += rw[2]; t3 += rw[3];
            u0 += rw[4]; u1 += rw[5]; u2 += rw[6]; u3 += rw[7];
        }
        partials[blk] = make_float4(t0, t1, t2, t3);
        partials2[blk] = make_float4(u0, u1, u2, u3);
    }
}

// ---------- reduce 1024 partials per batch (choose set via blockAny OR) + refined ----------
__global__ __launch_bounds__(256) void reduce_kernel(const float4* __restrict__ partials,
                                                     const float4* __restrict__ partials2,
                                                     const unsigned char* __restrict__ blockAny,
                                                     const float* __restrict__ pelvis,
                                                     float* __restrict__ out) {
    __shared__ float sh[4][256];
    __shared__ int anyFlag;
    int b = blockIdx.x, t = threadIdx.x;
    if (t == 0) anyFlag = 0;
    __syncthreads();
    if (blockAny[b * 256 + t]) anyFlag = 1;   // same-value race OK
    __syncthreads();
    const float4* P = anyFlag ? partials : partials2;

    float s0 = 0, s1 = 0, s2 = 0, s3 = 0;
#pragma unroll
    for (int i = 0; i < 4; ++i) {
        float4 p = P[b * 1024 + i * 256 + t];
        s0 += p.x; s1 += p.y; s2 += p.z; s3 += p.w;
    }
    sh[0][t] = s0; sh[1][t] = s1; sh[2][t] = s2; sh[3][t] = s3;
    __syncthreads();
    for (int st = 128; st > 0; st >>= 1) {
        if (t < st) {
            sh[0][t] += sh[0][t + st];
            sh[1][t] += sh[1][t + st];
            sh[2][t] += sh[2][t + st];
            sh[3][t] += sh[3][t + st];
        }
        __syncthreads();
    }
    if (t == 0) {
        float den = sh[0][0];
        float x = sh[1][0] / den;
        float y = sh[2][0] / den;
        float zz = sh[3][0] / den;
        bool bad = isnan(x) || isnan(y) || isnan(zz);
        out[b * 3 + 0] = bad ? pelvis[b * 3 + 0] : x;
        out[b * 3 + 1] = bad ? pelvis[b * 3 + 1] : y;
        out[b * 3 + 2] = bad ? pelvis[b * 3 + 2] : zz;
    }
}

extern "C" void kernel_launch(void* const* d_in, const int* in_sizes, int n_in,
                              void* d_out, int out_size, void* d_ws, size_t ws_size,
                              hipStream_t stream) {
    const float* points = (const float*)d_in[0];
    const float* fmap   = (const float*)d_in[1];
    const float* pelvis = (const float*)d_in[2];
    const float* Kmat   = (const float*)d_in[3];
    const float* bbx    = (const float*)d_in[4];
    const float* W1     = (const float*)d_in[5];
    const float* b1     = (const float*)d_in[6];
    const float* W2     = (const float*)d_in[7];
    const float* b2     = (const float*)d_in[8];
    float* out = (float*)d_out;

    char* ws = (char*)d_ws;
    unsigned char* occ2 = (unsigned char*)ws;
    unsigned char* bAny = (unsigned char*)(ws + BANY_OFF);
    float4* partials  = (float4*)(ws + PART_OFF);
    float4* partials2 = (float4*)(ws + PART2_OFF);
    ushort* fmapT   = (ushort*)(ws + FMT_OFF);
    ushort* w1p     = (ushort*)(ws + W1P_OFF);
    ushort* w2p     = (ushort*)(ws + W2P_OFF);

    hipMemsetAsync(ws, 0, BANY_OFF + 1024, stream);

    prep_kernel<<<2 * (BB * NN) / 256 + 1, 256, 0, stream>>>(points, pelvis, fmap,
                                                             occ2, bAny, fmapT,
                                                             W1, W2, w1p, w2p);
    voxel_kernel<<<(BB * G3) / 256, 256, 0, stream>>>(fmapT, pelvis, Kmat, bbx,
                                                      w1p, w2p, b1, b2,
                                                      (const ushort*)occ2,
                                                      partials, partials2, out + 12);
    reduce_kernel<<<BB, 256, 0, stream>>>(partials, partials2, bAny, pelvis, out);
}

// Round 12
// 131.053 us; speedup vs baseline: 1.2330x; 1.2330x over previous
//
#include <hip/hip_runtime.h>
#include <math.h>

#define BB 4
#define NN 65536
#define G 64
#define G3 (G*G*G)
#define CF 32
#define HF 128
#define WF 128
#define VSc 0.05f
#define R2c 1.5625f   // 1.25^2, exactly representable

// d_ws layout (bytes):
//  [0, 2*B*G3)          : occ2[b][g][2] bytes: byte0 = inb, byte1 = inb&nearby   2 MB (memset 0)
//  BANY_OFF             : blockAny[1024] bytes, 1 per points-block (memset 0)
//  PART_OFF             : partials  (nearby-gated) [4096] float4 (fully written)
//  PART2_OFF            : partials2 (inb-gated)    [4096] float4 (fully written)
//  FMT_OFF              : fmapT[B][H][W][C] bf16                                  4.2 MB
//  W1P_OFF              : W1 packed bf16 fragments [2][4][4][16][8]               8 KB
//  W2P_OFF              : W2 packed bf16 fragments (k-permuted) [2][4][16][8]     2 KB
#define BANY_OFF (2*BB*G3)
#define PART_OFF (BANY_OFF + 1024)
#define PART2_OFF (PART_OFF + 4096*16)
#define FMT_OFF  (PART2_OFF + 4096*16)
#define FMT_SZ   (BB*HF*WF*CF*2)
#define W1P_OFF  (FMT_OFF + FMT_SZ)
#define W2P_OFF  (W1P_OFF + 8192)

typedef __attribute__((ext_vector_type(8))) short short8;
typedef __attribute__((ext_vector_type(4))) float floatx4;

__device__ __forceinline__ ushort f2bf(float x) {
    union { float f; unsigned u; } v; v.f = x;
    unsigned r = v.u + 0x7FFF + ((v.u >> 16) & 1);   // RNE
    return (ushort)(r >> 16);
}

// packed f32x2 -> bf16x2 (lo = first operand), RNE. T12 recipe.
__device__ __forceinline__ unsigned cvt_pk_bf16(float lo, float hi) {
    unsigned r;
    asm("v_cvt_pk_bf16_f32 %0, %1, %2" : "=v"(r) : "v"(lo), "v"(hi));
    return r;
}

// ---------- fused prep: points scatter (ZERO atomics) + fmap transpose + weight pack ----------
// blocks 0..1023   : points (256 pts each) -> occ2 plain byte stores + blockAny
// blocks 1024..2047: [B,C,H,W] f32 -> [B,H,W,C] bf16 transpose
// block 2048       : W1/W2 bf16 fragment pre-pack
__global__ __launch_bounds__(256) void prep_kernel(const float* __restrict__ pts,
                                                   const float* __restrict__ pelvis,
                                                   const float* __restrict__ fmap,
                                                   unsigned char* __restrict__ occ2,
                                                   unsigned char* __restrict__ blockAny,
                                                   ushort* __restrict__ fmapT,
                                                   const float* __restrict__ W1,
                                                   const float* __restrict__ W2,
                                                   ushort* __restrict__ w1p,
                                                   ushort* __restrict__ w2p) {
    __shared__ float tile[CF][65];
    int bi = blockIdx.x;

    if (bi < (BB * NN) / 256) {
        // ---- points path: racy same-value byte stores, no atomics anywhere ----
        int idx = bi * 256 + threadIdx.x;
        int b = idx >> 16;                             // N = 65536
        const float* p = pts + (size_t)idx * 3;
        float px = p[0], py = p[1], pz = p[2];
        float ax = pelvis[b * 3 + 0], ay = pelvis[b * 3 + 1], az = pelvis[b * 3 + 2];

        float dx = px - ax, dy = py - ay, dz = pz - az;
        float rxy = dx * dx + dy * dy;
        float d0 = dz * dz;
        float dm = (dz + 0.5f) * (dz + 0.5f);
        float dp = (dz - 0.5f) * (dz - 0.5f);
        float mind2 = rxy + fminf(d0, fminf(dm, dp));
        bool nearby = mind2 <= R2c;

        int vx = (int)floorf(px / VSc);
        int vy = (int)floorf(py / VSc);
        int vz = (int)floorf(pz / VSc);
        int v0x = (int)floorf(ax / VSc) - 32;
        int v0y = (int)floorf(ay / VSc) - 32;
        int v0z = (int)floorf(az / VSc) - 32;
        int lx = vx - v0x, ly = vy - v0y, lz = vz - v0z;
        bool inb = ((unsigned)lx < 64u) && ((unsigned)ly < 64u) && ((unsigned)lz < 64u);
        if (inb) {
            int flat = b * G3 + (lx << 12) + (ly << 6) + lz;
            if (nearby) {
                *(ushort*)(occ2 + 2 * (size_t)flat) = 0x0101;   // inb + nearby, one aligned store
            } else {
                occ2[2 * (size_t)flat] = 1;                      // inb only
            }
        }
        unsigned long long bal = __ballot(nearby);
        if ((threadIdx.x & 63) == 0 && bal != 0ULL) blockAny[bi] = 1;  // same-value race OK
        return;
    }

    if (bi == 2 * (BB * NN) / 256) {
        // ---- weight pre-pack path ----
        int t = threadIdx.x;
        // W1p: 512 short8 ; s = ((kt*4+nt)*4+quad)*16 + n16
        for (int s = t; s < 512; s += 256) {
            int kt = s >> 8, nt = (s >> 6) & 3, quad = (s >> 4) & 3, n16 = s & 15;
            short8 w;
#pragma unroll
            for (int j = 0; j < 8; ++j) {
                int kk = kt * 32 + quad * 8 + j;
                // feat k 0..31 -> W1 row 3+k ; feat k 32..34 -> W1 row k-32 ; else 0
                int row = (kk < 32) ? (3 + kk) : (kk - 32);
                w[j] = (kk < 35) ? (short)f2bf(W1[row * 64 + nt * 16 + n16]) : (short)0;
            }
            *(short8*)(w1p + s * 8) = w;
        }
        // W2p: 128 short8 ; physical k = kt*32+quad*8+j maps to logical h-col
        // c = (phys&3)*16 + (phys>>2)  (matches relu-store permutation p = n16*4+nt)
        if (t < 128) {
            int kt = t >> 6, quad = (t >> 4) & 3, n16 = t & 15;
            short8 w;
#pragma unroll
            for (int j = 0; j < 8; ++j) {
                int phys = kt * 32 + quad * 8 + j;
                int c = (phys & 3) * 16 + (phys >> 2);
                w[j] = (n16 < 12) ? (short)f2bf(W2[c * 12 + n16]) : (short)0;
            }
            *(short8*)(w2p + t * 8) = w;
        }
        return;
    }

    // ---- transpose path ----
    int tb = bi - (BB * NN) / 256;
    int xc = (tb & 1) * 64;
    int y  = (tb >> 1) & (HF - 1);
    int b  = tb >> 8;
    int t = threadIdx.x;
#pragma unroll
    for (int i = 0; i < 8; ++i) {
        int e = i * 256 + t;
        int c = e >> 6, p = e & 63;
        tile[c][p] = fmap[(((size_t)b * CF + c) * HF + y) * WF + xc + p];
    }
    __syncthreads();
    // 64 pixels x 32 ch = 1024 uints (bf16 pairs)
    unsigned* dst32 = (unsigned*)fmapT;
#pragma unroll
    for (int i = 0; i < 4; ++i) {
        int e = i * 256 + t;
        int pix = e >> 4, cp = e & 15;
        unsigned val = cvt_pk_bf16(tile[cp * 2][pix], tile[cp * 2 + 1][pix]);
        dst32[((((size_t)b * HF + y) * WF + xc + pix) << 4) + cp] = val;
    }
}

// ---------- voxel: bilinear gather (bf16) + MFMA MLP ----------
// Per wave: 64 voxels. A-tile [64 x 64] bf16 in LDS (row stride 72 ushorts = 144 B).
// Layer1: C1[64x64] = A(feat) * W1p ; Layer2 (cols permuted p=n16*4+nt): C2 = A(h) * W2p.
// Dual softmax accumulation (nearby-gated and inb-gated); reduce picks per blockAny.
// Output: PLAIN cached stores, wave-coalesced via LDS O re-read -- each store instr
// covers a contiguous 1 KB span (16 full 64B lines).
// MEASURED-CLOSED levers (do not retry):
//   - NT stores: R6, write amplification + L3 eviction of fmapT.
//   - 5 blk/CU (8KB swizzled LDS): R6/R8/R11 all regress ~20-28 us; FETCH/WRITE
//     explode regardless of store pattern; occupancy doesn't even rise (LDS pool
//     exactly full). Keep 4 blk/CU + 72-stride LDS.
// launch_bounds(256,4): 4 blocks/CU (LDS 4*37376 = 149.5 KB <= 160 KB), 16 waves/CU.
__global__ __launch_bounds__(256, 4) void voxel_kernel(
    const ushort* __restrict__ fmapT, const float* __restrict__ pelvis,
    const float* __restrict__ Kmat, const float* __restrict__ bbx,
    const ushort* __restrict__ w1p, const ushort* __restrict__ w2p,
    const float* __restrict__ b1, const float* __restrict__ b2,
    const ushort* __restrict__ occ2,
    float4* __restrict__ partials, float4* __restrict__ partials2,
    float* __restrict__ outBig) {
    __shared__ __align__(16) char ldsRaw[4][9216];
    __shared__ float red[4][8];

    int blk = blockIdx.x;
    int b = blk >> 10;
    int wv = threadIdx.x >> 6, lane = threadIdx.x & 63;
    int quad = lane >> 4, n16 = lane & 15;
    int g = ((blk & 1023) << 8) + (wv << 6) + lane;
    ushort* A = (ushort*)ldsRaw[wv];

    // early load used only in the tail
    ushort oc2 = occ2[(size_t)b * G3 + g];   // lo byte = inb, hi byte = inb&nearby

    float ax = pelvis[b * 3 + 0], ay = pelvis[b * 3 + 1], az = pelvis[b * 3 + 2];
    float fx = Kmat[b * 9 + 0], fy = Kmat[b * 9 + 4];
    float cxp = Kmat[b * 9 + 2], cyp = Kmat[b * 9 + 5];
    float l = bbx[b * 4 + 0], t = bbx[b * 4 + 1];
    float r = bbx[b * 4 + 2], btm = bbx[b * 4 + 3];
    float inv_w = 1.0f / (r - l), inv_h = 1.0f / (btm - t);

    int v0x = (int)floorf(ax / VSc) - 32;
    int v0y = (int)floorf(ay / VSc) - 32;
    int v0z = (int)floorf(az / VSc) - 32;

    int gx = g >> 12, gy = (g >> 6) & 63, gz = g & 63;
    float cxx = (float)(v0x + gx) * VSc + 0.025f;
    float cyy = (float)(v0y + gy) * VSc + 0.025f;
    float czz = (float)(v0z + gz) * VSc + 0.025f;

    float z = czz;
    float u = cxx / z * fx + cxp;
    float vp = cyy / z * fy + cyp;
    float uu = (u - l) * inv_w * (float)(WF - 1);
    float vv = (vp - t) * inv_h * (float)(HF - 1);
    float x0f = floorf(uu), y0f = floorf(vv);
    float wx = uu - x0f, wy = vv - y0f;
    int x0 = (int)x0f, y0 = (int)y0f;
    int x1 = x0 + 1, y1 = y0 + 1;
    bool mx0 = (unsigned)x0 < (unsigned)WF;
    bool mx1 = (unsigned)x1 < (unsigned)WF;
    bool my0 = (unsigned)y0 < (unsigned)HF;
    bool my1 = (unsigned)y1 < (unsigned)HF;
    int xc0 = min(max(x0, 0), WF - 1), xc1 = min(max(x1, 0), WF - 1);
    int yc0 = min(max(y0, 0), HF - 1), yc1 = min(max(y1, 0), HF - 1);

    // ---- stage all 4 corners (bf16, 64B each) into registers ----
    const ushort* fb = fmapT + (size_t)b * HF * WF * CF;
    const uint4* q00 = (const uint4*)(fb + (size_t)(yc0 * WF + xc0) * CF);
    const uint4* q10 = (const uint4*)(fb + (size_t)(yc0 * WF + xc1) * CF);
    const uint4* q01 = (const uint4*)(fb + (size_t)(yc1 * WF + xc0) * CF);
    const uint4* q11 = (const uint4*)(fb + (size_t)(yc1 * WF + xc1) * CF);
    unsigned r00[16], r10[16], r01[16], r11[16];
#pragma unroll
    for (int j = 0; j < 4; ++j) {
        *(uint4*)(r00 + 4 * j) = q00[j];
        *(uint4*)(r10 + 4 * j) = q10[j];
        *(uint4*)(r01 + 4 * j) = q01[j];
        *(uint4*)(r11 + 4 * j) = q11[j];
    }

    float w00 = (1.0f - wx) * (1.0f - wy) * ((mx0 && my0) ? 1.0f : 0.0f);
    float w10 = wx * (1.0f - wy) * ((mx1 && my0) ? 1.0f : 0.0f);
    float w01 = (1.0f - wx) * wy * ((mx0 && my1) ? 1.0f : 0.0f);
    float w11 = wx * wy * ((mx1 && my1) ? 1.0f : 0.0f);

    // ---- bilinear combine in f32 (bf16 unpack = 1 VALU op each) ----
    float feat[35];
    feat[32] = ax - cxx;
    feat[33] = ay - cyy;
    feat[34] = az - czz;
#pragma unroll
    for (int d = 0; d < 16; ++d) {
        float a00l = __uint_as_float(r00[d] << 16), a00h = __uint_as_float(r00[d] & 0xFFFF0000u);
        float a10l = __uint_as_float(r10[d] << 16), a10h = __uint_as_float(r10[d] & 0xFFFF0000u);
        float a01l = __uint_as_float(r01[d] << 16), a01h = __uint_as_float(r01[d] & 0xFFFF0000u);
        float a11l = __uint_as_float(r11[d] << 16), a11h = __uint_as_float(r11[d] & 0xFFFF0000u);
        feat[2 * d]     = fmaf(a11l, w11, fmaf(a01l, w01, fmaf(a10l, w10, a00l * w00)));
        feat[2 * d + 1] = fmaf(a11h, w11, fmaf(a01h, w01, fmaf(a10h, w10, a00h * w00)));
    }

    // ---- pack feat -> bf16 LDS A-tile (K padded to 64) ----
#pragma unroll
    for (int i = 0; i < 4; ++i) {
        uint4 v;
        v.x = cvt_pk_bf16(feat[8 * i + 0], feat[8 * i + 1]);
        v.y = cvt_pk_bf16(feat[8 * i + 2], feat[8 * i + 3]);
        v.z = cvt_pk_bf16(feat[8 * i + 4], feat[8 * i + 5]);
        v.w = cvt_pk_bf16(feat[8 * i + 6], feat[8 * i + 7]);
        *(uint4*)(A + lane * 72 + i * 8) = v;
    }
    {
        uint4 v;
        v.x = cvt_pk_bf16(feat[32], feat[33]);
        v.y = cvt_pk_bf16(feat[34], 0.0f);
        v.z = 0; v.w = 0;
        *(uint4*)(A + lane * 72 + 32) = v;
        uint4 z4 = {0, 0, 0, 0};
        *(uint4*)(A + lane * 72 + 40) = z4;
        *(uint4*)(A + lane * 72 + 48) = z4;
        *(uint4*)(A + lane * 72 + 56) = z4;
    }

    // ---- weight B-fragments: coalesced 16B loads of pre-packed bf16 ----
    const short8* W1v = (const short8*)w1p;
    const short8* W2v = (const short8*)w2p;
    short8 B1f[2][4];
#pragma unroll
    for (int kt = 0; kt < 2; ++kt)
#pragma unroll
        for (int nt = 0; nt < 4; ++nt)
            B1f[kt][nt] = W1v[((kt * 4 + nt) * 4 + quad) * 16 + n16];
    short8 B2f[2];
#pragma unroll
    for (int kt = 0; kt < 2; ++kt)
        B2f[kt] = W2v[(kt * 4 + quad) * 16 + n16];
    float b1v[4];
#pragma unroll
    for (int nt = 0; nt < 4; ++nt) b1v[nt] = b1[nt * 16 + n16];
    float b2v = (n16 < 12) ? b2[n16] : 0.0f;

    // ---- layer 1: 32 MFMA ----
    floatx4 c1[4][4];
#pragma unroll
    for (int mt = 0; mt < 4; ++mt)
#pragma unroll
        for (int nt = 0; nt < 4; ++nt) {
            floatx4 c = {b1v[nt], b1v[nt], b1v[nt], b1v[nt]};
            c1[mt][nt] = c;
        }
#pragma unroll
    for (int mt = 0; mt < 4; ++mt) {
        short8 a0 = *(short8*)(A + (mt * 16 + n16) * 72 + quad * 8);
        short8 a1 = *(short8*)(A + (mt * 16 + n16) * 72 + 32 + quad * 8);
#pragma unroll
        for (int nt = 0; nt < 4; ++nt) {
            c1[mt][nt] = __builtin_amdgcn_mfma_f32_16x16x32_bf16(a0, B1f[0][nt], c1[mt][nt], 0, 0, 0);
            c1[mt][nt] = __builtin_amdgcn_mfma_f32_16x16x32_bf16(a1, B1f[1][nt], c1[mt][nt], 0, 0, 0);
        }
    }

    // ---- relu -> bf16 -> LDS, nt-packed b64 writes (physical col p = n16*4+nt) ----
#pragma unroll
    for (int mt = 0; mt < 4; ++mt)
#pragma unroll
        for (int rr = 0; rr < 4; ++rr) {
            float h0 = fmaxf(c1[mt][0][rr], 0.0f);
            float h1 = fmaxf(c1[mt][1][rr], 0.0f);
            float h2 = fmaxf(c1[mt][2][rr], 0.0f);
            float h3 = fmaxf(c1[mt][3][rr], 0.0f);
            uint2 uv;
            uv.x = cvt_pk_bf16(h0, h1);
            uv.y = cvt_pk_bf16(h2, h3);
            *(uint2*)(A + (mt * 16 + quad * 4 + rr) * 72 + n16 * 4) = uv;
        }

    // ---- layer 2: 8 MFMA (W2 rows pre-permuted to match) ----
    floatx4 c2[4];
#pragma unroll
    for (int mt = 0; mt < 4; ++mt) {
        floatx4 c = {b2v, b2v, b2v, b2v};
        c2[mt] = c;
    }
#pragma unroll
    for (int mt = 0; mt < 4; ++mt) {
        short8 a0 = *(short8*)(A + (mt * 16 + n16) * 72 + quad * 8);
        short8 a1 = *(short8*)(A + (mt * 16 + n16) * 72 + 32 + quad * 8);
        c2[mt] = __builtin_amdgcn_mfma_f32_16x16x32_bf16(a0, B2f[0], c2[mt], 0, 0, 0);
        c2[mt] = __builtin_amdgcn_mfma_f32_16x16x32_bf16(a1, B2f[1], c2[mt], 0, 0, 0);
    }

    // ---- C2 -> LDS (stride 20 floats) ----
    float* O = (float*)ldsRaw[wv];
#pragma unroll
    for (int mt = 0; mt < 4; ++mt)
#pragma unroll
        for (int rr = 0; rr < 4; ++rr)
            O[(mt * 16 + quad * 4 + rr) * 20 + n16] = c2[mt][rr];

    // ---- wave-coalesced PLAIN output: 768 floats contiguous; lane i -> float4s i, i+64, i+128 ----
    // Each store instruction writes a contiguous 1 KB span = 16 full 64B lines.
    size_t base = (size_t)(b * G3 + ((blk & 1023) << 8) + (wv << 6)) * 12;
#pragma unroll
    for (int j = 0; j < 3; ++j) {
        int k = 4 * lane + 256 * j;          // float index within wave's 768-float block
        int vx12 = k / 12;                    // voxel within wave
        int c12 = k - vx12 * 12;              // component (0,4,8 - never crosses voxel)
        floatx4 val = *(floatx4*)(O + vx12 * 20 + c12);
        *(floatx4*)(outBig + base + k) = val;
    }

    // own voxel's out[0..3] for the softmax tail
    floatx4 o0 = *(floatx4*)(O + lane * 20);

    // ---- dual softmax accumulation, fixed max M = 1 ----
    float sig = 1.0f / (1.0f + __expf(-o0.x));
    float e = __expf(sig - 1.0f);
    float wxx = cxx + o0.y, wyy = cyy + o0.z, wzz = czz + o0.w;
    float eN = ((oc2 >> 8) != 0) ? e : 0.0f;      // nearby-gated (any==1 case)
    float eI = ((oc2 & 0xFF) != 0) ? e : 0.0f;    // inb-gated   (any==0 case)
    float sN0 = eN, sN1 = eN * wxx, sN2 = eN * wyy, sN3 = eN * wzz;
    float sI0 = eI, sI1 = eI * wxx, sI2 = eI * wyy, sI3 = eI * wzz;
#pragma unroll
    for (int off = 32; off > 0; off >>= 1) {
        sN0 += __shfl_down(sN0, off, 64);
        sN1 += __shfl_down(sN1, off, 64);
        sN2 += __shfl_down(sN2, off, 64);
        sN3 += __shfl_down(sN3, off, 64);
        sI0 += __shfl_down(sI0, off, 64);
        sI1 += __shfl_down(sI1, off, 64);
        sI2 += __shfl_down(sI2, off, 64);
        sI3 += __shfl_down(sI3, off, 64);
    }
    if ((threadIdx.x & 63) == 0) {
        red[wv][0] = sN0; red[wv][1] = sN1; red[wv][2] = sN2; red[wv][3] = sN3;
        red[wv][4] = sI0; red[wv][5] = sI1; red[wv][6] = sI2; red[wv][7] = sI3;
    }
    __syncthreads();
    if (threadIdx.x == 0) {
        float t0 = red[0][0] + red[1][0] + red[2][0] + red[3][0];
        float t1 = red[0][1] + red[1][1] + red[2][1] + red[3][1];
        float t2 = red[0][2] + red[1][2] + red[2][2] + red[3][2];
        float t3 = red[0][3] + red[1][3] + red[2][3] + red[3][3];
        partials[blk] = make_float4(t0, t1, t2, t3);
        float u0 = red[0][4] + red[1][4] + red[2][4] + red[3][4];
        float u1 = red[0][5] + red[1][5] + red[2][5] + red[3][5];
        float u2 = red[0][6] + red[1][6] + red[2][6] + red[3][6];
        float u3 = red[0][7] + red[1][7] + red[2][7] + red[3][7];
        partials2[blk] = make_float4(u0, u1, u2, u3);
    }
}

// ---------- reduce 1024 partials per batch (choose set via blockAny OR) + refined ----------
__global__ __launch_bounds__(256) void reduce_kernel(const float4* __restrict__ partials,
                                                     const float4* __restrict__ partials2,
                                                     const unsigned char* __restrict__ blockAny,
                                                     const float* __restrict__ pelvis,
                                                     float* __restrict__ out) {
    __shared__ float sh[4][256];
    __shared__ int anyFlag;
    int b = blockIdx.x, t = threadIdx.x;
    if (t == 0) anyFlag = 0;
    __syncthreads();
    if (blockAny[b * 256 + t]) anyFlag = 1;   // same-value race OK
    __syncthreads();
    const float4* P = anyFlag ? partials : partials2;

    float s0 = 0, s1 = 0, s2 = 0, s3 = 0;
#pragma unroll
    for (int i = 0; i < 4; ++i) {
        float4 p = P[b * 1024 + i * 256 + t];
        s0 += p.x; s1 += p.y; s2 += p.z; s3 += p.w;
    }
    sh[0][t] = s0; sh[1][t] = s1; sh[2][t] = s2; sh[3][t] = s3;
    __syncthreads();
    for (int st = 128; st > 0; st >>= 1) {
        if (t < st) {
            sh[0][t] += sh[0][t + st];
            sh[1][t] += sh[1][t + st];
            sh[2][t] += sh[2][t + st];
            sh[3][t] += sh[3][t + st];
        }
        __syncthreads();
    }
    if (t == 0) {
        float den = sh[0][0];
        float x = sh[1][0] / den;
        float y = sh[2][0] / den;
        float zz = sh[3][0] / den;
        bool bad = isnan(x) || isnan(y) || isnan(zz);
        out[b * 3 + 0] = bad ? pelvis[b * 3 + 0] : x;
        out[b * 3 + 1] = bad ? pelvis[b * 3 + 1] : y;
        out[b * 3 + 2] = bad ? pelvis[b * 3 + 2] : zz;
    }
}

extern "C" void kernel_launch(void* const* d_in, const int* in_sizes, int n_in,
                              void* d_out, int out_size, void* d_ws, size_t ws_size,
                              hipStream_t stream) {
    const float* points = (const float*)d_in[0];
    const float* fmap   = (const float*)d_in[1];
    const float* pelvis = (const float*)d_in[2];
    const float* Kmat   = (const float*)d_in[3];
    const float* bbx    = (const float*)d_in[4];
    const float* W1     = (const float*)d_in[5];
    const float* b1     = (const float*)d_in[6];
    const float* W2     = (const float*)d_in[7];
    const float* b2     = (const float*)d_in[8];
    float* out = (float*)d_out;

    char* ws = (char*)d_ws;
    unsigned char* occ2 = (unsigned char*)ws;
    unsigned char* bAny = (unsigned char*)(ws + BANY_OFF);
    float4* partials  = (float4*)(ws + PART_OFF);
    float4* partials2 = (float4*)(ws + PART2_OFF);
    ushort* fmapT   = (ushort*)(ws + FMT_OFF);
    ushort* w1p     = (ushort*)(ws + W1P_OFF);
    ushort* w2p     = (ushort*)(ws + W2P_OFF);

    hipMemsetAsync(ws, 0, BANY_OFF + 1024, stream);

    prep_kernel<<<2 * (BB * NN) / 256 + 1, 256, 0, stream>>>(points, pelvis, fmap,
                                                             occ2, bAny, fmapT,
                                                             W1, W2, w1p, w2p);
    voxel_kernel<<<(BB * G3) / 256, 256, 0, stream>>>(fmapT, pelvis, Kmat, bbx,
                                                      w1p, w2p, b1, b2,
                                                      (const ushort*)occ2,
                                                      partials, partials2, out + 12);
    reduce_kernel<<<BB, 256, 0, stream>>>(partials, partials2, bAny, pelvis, out);
}